// Round 1
// baseline (406.778 us; speedup 1.0000x reference)
//
#include <hip/hip_runtime.h>

#define NROWS 8192
#define DDIM  256
#define NBINS 129

typedef float f32x4 __attribute__((ext_vector_type(4)));
typedef short bf16x8 __attribute__((ext_vector_type(8)));

__device__ __forceinline__ float wave_red(float v) {
#pragma unroll
    for (int m = 32; m; m >>= 1) v += __shfl_xor(v, m, 64);
    return v;
}

__device__ __forceinline__ unsigned bfbits(float f) {
    union { float f; unsigned u; } v; v.f = f;
    return (v.u + 0x7FFFu + ((v.u >> 16) & 1u)) >> 16;
}

// ---------------------------------------------------------------------------
// Kernel 1: per-row — spatial MSE partials, L2 norms, bf16 normalized write,
// direct-DFT magnitudes + frequency MSE partials. One wave per row.
// ---------------------------------------------------------------------------
__global__ __launch_bounds__(256) void k_row(const float* __restrict__ clean,
                                             const float* __restrict__ turb,
                                             unsigned short* __restrict__ cnb,
                                             unsigned short* __restrict__ tnb,
                                             float* __restrict__ accum) {
    __shared__ float2 xy[4][DDIM];
    const int wid  = threadIdx.x >> 6;
    const int lane = threadIdx.x & 63;
    const int row  = blockIdx.x * 4 + wid;

    const float4 xc = ((const float4*)(clean + row * DDIM))[lane];
    const float4 xt = ((const float4*)(turb  + row * DDIM))[lane];

    // stage interleaved row into LDS for the DFT broadcast reads
    xy[wid][lane * 4 + 0] = make_float2(xc.x, xt.x);
    xy[wid][lane * 4 + 1] = make_float2(xc.y, xt.y);
    xy[wid][lane * 4 + 2] = make_float2(xc.z, xt.z);
    xy[wid][lane * 4 + 3] = make_float2(xc.w, xt.w);

    float dsq = (xc.x - xt.x) * (xc.x - xt.x) + (xc.y - xt.y) * (xc.y - xt.y)
              + (xc.z - xt.z) * (xc.z - xt.z) + (xc.w - xt.w) * (xc.w - xt.w);
    float sx2 = xc.x * xc.x + xc.y * xc.y + xc.z * xc.z + xc.w * xc.w;
    float sy2 = xt.x * xt.x + xt.y * xt.y + xt.z * xt.z + xt.w * xt.w;
    float nyc = xc.x - xc.y + xc.z - xc.w;   // (-1)^n partial (n = lane*4+j)
    float nyt = xt.x - xt.y + xt.z - xt.w;

    dsq = wave_red(dsq);
    sx2 = wave_red(sx2);
    sy2 = wave_red(sy2);
    nyc = wave_red(nyc);
    nyt = wave_red(nyt);

    const float inv_nc = 1.0f / fmaxf(sqrtf(sx2), 1e-12f);
    const float inv_nt = 1.0f / fmaxf(sqrtf(sy2), 1e-12f);

    // normalized bf16 write (8B per lane, coalesced)
    uint2 pc, pt;
    pc.x = bfbits(xc.x * inv_nc) | (bfbits(xc.y * inv_nc) << 16);
    pc.y = bfbits(xc.z * inv_nc) | (bfbits(xc.w * inv_nc) << 16);
    pt.x = bfbits(xt.x * inv_nt) | (bfbits(xt.y * inv_nt) << 16);
    pt.y = bfbits(xt.z * inv_nt) | (bfbits(xt.w * inv_nt) << 16);
    ((uint2*)(cnb + row * DDIM))[lane] = pc;
    ((uint2*)(tnb + row * DDIM))[lane] = pt;

    __syncthreads();

    // Nyquist bin (k=128): F = sum x_n * (-1)^n (real)
    float freq_local = 0.0f;
    if (lane == 0) {
        float d = fabsf(nyc) - fabsf(nyt);
        freq_local = d * d;
    }

    // bins k = lane, lane+64 via twiddle-recurrence DFT
#pragma unroll
    for (int p = 0; p < 2; ++p) {
        const int k = lane + p * 64;
        const float w = (float)k * 0.0245436926f; // 2*pi/256
        float sw, cw;
        __sincosf(w, &sw, &cw);
        float c = 1.0f, s = 0.0f;
        float cr = 0.0f, ci = 0.0f, tr = 0.0f, ti = 0.0f;
#pragma unroll 8
        for (int n = 0; n < 256; ++n) {
            float2 v = xy[wid][n];
            cr = fmaf(v.x, c, cr);
            ci = fmaf(v.x, s, ci);
            tr = fmaf(v.y, c, tr);
            ti = fmaf(v.y, s, ti);
            float nc2 = fmaf(cw, c, -sw * s);
            s = fmaf(sw, c, cw * s);
            c = nc2;
        }
        float mc = sqrtf(cr * cr + ci * ci);
        float mt = sqrtf(tr * tr + ti * ti);
        float d = mc - mt;
        freq_local += d * d;
    }

    freq_local = wave_red(freq_local);
    if (lane == 0) {
        atomicAdd(&accum[0], dsq);
        atomicAdd(&accum[1], freq_local);
    }
}

// ---------------------------------------------------------------------------
// Kernel 2: 128x128-tile bf16 MFMA GEMM (sim = cn . tn^T / T) fused with
// exp + label mask + per-row sums (atomics into all_sum / pos_sum).
// ---------------------------------------------------------------------------
#define BM 128
#define BN 128
#define BK 64
#define LDP 72   // padded LDS K-stride (elements); 144 B row stride -> 2-way-free banks

__global__ __launch_bounds__(256) void k_gemm(const unsigned short* __restrict__ cnb,
                                              const unsigned short* __restrict__ tnb,
                                              const int* __restrict__ sid,
                                              float* __restrict__ all_sum,
                                              float* __restrict__ pos_sum) {
    __shared__ unsigned short As[BM][LDP];
    __shared__ unsigned short Bs[BN][LDP];
    __shared__ int sidI[BM], sidJ[BN];

    const int t = threadIdx.x;
    const int i0 = blockIdx.y * BM;
    const int j0 = blockIdx.x * BN;

    if (t < 128) sidI[t] = sid[i0 + t];
    else         sidJ[t - 128] = sid[j0 + t - 128];

    const int wid  = t >> 6;
    const int lane = t & 63;
    const int wrow = (wid >> 1) * 64;
    const int wcol = (wid & 1) * 64;

    f32x4 acc[4][4];
#pragma unroll
    for (int m = 0; m < 4; ++m)
#pragma unroll
        for (int n = 0; n < 4; ++n)
            acc[m][n] = (f32x4){0.f, 0.f, 0.f, 0.f};

    for (int kt = 0; kt < DDIM / BK; ++kt) {
        if (kt) __syncthreads();
        // stage tiles (reg-staged so the pad is legal)
#pragma unroll
        for (int it = 0; it < 4; ++it) {
            const int idx = (it * 256 + t) * 8;  // element in 128x64 tile
            const int r = idx >> 6;
            const int k = idx & 63;
            bf16x8 va = *(const bf16x8*)(cnb + (i0 + r) * DDIM + kt * BK + k);
            bf16x8 vb = *(const bf16x8*)(tnb + (j0 + r) * DDIM + kt * BK + k);
            *(bf16x8*)&As[r][k] = va;
            *(bf16x8*)&Bs[r][k] = vb;
        }
        __syncthreads();
#pragma unroll
        for (int kk = 0; kk < BK / 32; ++kk) {
            const int kb = kk * 32 + (lane >> 4) * 8;
            bf16x8 af[4], bfr[4];
#pragma unroll
            for (int m = 0; m < 4; ++m)
                af[m] = *(const bf16x8*)&As[wrow + m * 16 + (lane & 15)][kb];
#pragma unroll
            for (int n = 0; n < 4; ++n)
                bfr[n] = *(const bf16x8*)&Bs[wcol + n * 16 + (lane & 15)][kb];
#pragma unroll
            for (int m = 0; m < 4; ++m)
#pragma unroll
                for (int n = 0; n < 4; ++n)
                    acc[m][n] = __builtin_amdgcn_mfma_f32_16x16x32_bf16(
                        af[m], bfr[n], acc[m][n], 0, 0, 0);
        }
    }

    // epilogue: exp, mask, row-reduce, atomic accumulate
    const float invT = 1.0f / 0.07f;
#pragma unroll
    for (int m = 0; m < 4; ++m) {
        const int rbase = wrow + m * 16 + ((lane >> 4) << 2);
        int si[4];
#pragma unroll
        for (int r = 0; r < 4; ++r) si[r] = sidI[rbase + r];
        float rs_all[4] = {0.f, 0.f, 0.f, 0.f};
        float rs_pos[4] = {0.f, 0.f, 0.f, 0.f};
#pragma unroll
        for (int n = 0; n < 4; ++n) {
            const int col = wcol + n * 16 + (lane & 15);
            const int sj = sidJ[col];
#pragma unroll
            for (int r = 0; r < 4; ++r) {
                float e = __expf(acc[m][n][r] * invT);
                rs_all[r] += e;
                rs_pos[r] += (si[r] == sj) ? e : 0.0f;
            }
        }
#pragma unroll
        for (int msk = 1; msk < 16; msk <<= 1) {
#pragma unroll
            for (int r = 0; r < 4; ++r) {
                rs_all[r] += __shfl_xor(rs_all[r], msk, 64);
                rs_pos[r] += __shfl_xor(rs_pos[r], msk, 64);
            }
        }
        if ((lane & 15) == 0) {
#pragma unroll
            for (int r = 0; r < 4; ++r) {
                atomicAdd(&all_sum[i0 + rbase + r], rs_all[r]);
                atomicAdd(&pos_sum[i0 + rbase + r], rs_pos[r]);
            }
        }
    }
}

// ---------------------------------------------------------------------------
// Kernel 3: final reduction -> 4 outputs
// ---------------------------------------------------------------------------
__global__ __launch_bounds__(256) void k_final(const float* __restrict__ all_sum,
                                               const float* __restrict__ pos_sum,
                                               const float* __restrict__ accum,
                                               float* __restrict__ out) {
    __shared__ float red[256];
    float c = 0.0f;
    for (int i = threadIdx.x; i < NROWS; i += 256) {
        c += logf(all_sum[i] + 1e-8f) - logf(pos_sum[i]);
    }
    red[threadIdx.x] = c;
    __syncthreads();
#pragma unroll
    for (int s = 128; s > 0; s >>= 1) {
        if (threadIdx.x < s) red[threadIdx.x] += red[threadIdx.x + s];
        __syncthreads();
    }
    if (threadIdx.x == 0) {
        float contrastive = red[0] / (float)NROWS;
        float spatial = accum[0] / (float)(NROWS * DDIM);
        float frequency = accum[1] / (float)(NROWS * NBINS);
        float total = spatial + frequency + 0.5f * contrastive;
        out[0] = total;
        out[1] = spatial;
        out[2] = frequency;
        out[3] = contrastive;
    }
}

// ---------------------------------------------------------------------------
extern "C" void kernel_launch(void* const* d_in, const int* in_sizes, int n_in,
                              void* d_out, int out_size, void* d_ws, size_t ws_size,
                              hipStream_t stream) {
    const float* clean = (const float*)d_in[0];
    const float* turb  = (const float*)d_in[1];
    const int*   sids  = (const int*)d_in[2];

    char* ws = (char*)d_ws;
    unsigned short* cnb = (unsigned short*)ws;                       // 4 MB
    unsigned short* tnb = (unsigned short*)(ws + 4194304);           // 4 MB
    float* all_sum = (float*)(ws + 8388608);                         // 32 KB
    float* pos_sum = (float*)(ws + 8388608 + 32768);                 // 32 KB
    float* accum   = (float*)(ws + 8388608 + 65536);                 // 8 B

    hipMemsetAsync(ws + 8388608, 0, 65536 + 64, stream);

    hipLaunchKernelGGL(k_row, dim3(NROWS / 4), dim3(256), 0, stream,
                       clean, turb, cnb, tnb, accum);
    hipLaunchKernelGGL(k_gemm, dim3(NROWS / BN, NROWS / BM), dim3(256), 0, stream,
                       cnb, tnb, sids, all_sum, pos_sum);
    hipLaunchKernelGGL(k_final, dim3(1), dim3(256), 0, stream,
                       all_sum, pos_sum, accum, (float*)d_out);
}

// Round 2
// 328.447 us; speedup vs baseline: 1.2385x; 1.2385x over previous
//
#include <hip/hip_runtime.h>

#define NROWS 8192
#define DDIM  256
#define NBINS 129

typedef float f32x4 __attribute__((ext_vector_type(4)));
typedef short bf16x8 __attribute__((ext_vector_type(8)));

__device__ __forceinline__ float wave_red(float v) {
#pragma unroll
    for (int m = 32; m; m >>= 1) v += __shfl_xor(v, m, 64);
    return v;
}

__device__ __forceinline__ unsigned bfbits(float f) {
    union { float f; unsigned u; } v; v.f = f;
    return (v.u + 0x7FFFu + ((v.u >> 16) & 1u)) >> 16;
}

__device__ __forceinline__ void gload_lds16(const void* g, void* l) {
    __builtin_amdgcn_global_load_lds((const __attribute__((address_space(1))) void*)g,
                                     (__attribute__((address_space(3))) void*)l,
                                     16, 0, 0);
}

// ---------------------------------------------------------------------------
// Kernel 1: streaming per-row pass — spatial MSE partial, L2 norms,
// normalized bf16 write. One wave per row, no LDS, no DFT.
// ---------------------------------------------------------------------------
__global__ __launch_bounds__(256) void k_row(const float* __restrict__ clean,
                                             const float* __restrict__ turb,
                                             unsigned short* __restrict__ cnb,
                                             unsigned short* __restrict__ tnb,
                                             float* __restrict__ accum) {
    const int wid  = threadIdx.x >> 6;
    const int lane = threadIdx.x & 63;
    const int row  = blockIdx.x * 4 + wid;

    const float4 xc = ((const float4*)(clean + row * DDIM))[lane];
    const float4 xt = ((const float4*)(turb  + row * DDIM))[lane];

    float dsq = (xc.x - xt.x) * (xc.x - xt.x) + (xc.y - xt.y) * (xc.y - xt.y)
              + (xc.z - xt.z) * (xc.z - xt.z) + (xc.w - xt.w) * (xc.w - xt.w);
    float sx2 = xc.x * xc.x + xc.y * xc.y + xc.z * xc.z + xc.w * xc.w;
    float sy2 = xt.x * xt.x + xt.y * xt.y + xt.z * xt.z + xt.w * xt.w;

    dsq = wave_red(dsq);
    sx2 = wave_red(sx2);
    sy2 = wave_red(sy2);

    const float inv_nc = 1.0f / fmaxf(sqrtf(sx2), 1e-12f);
    const float inv_nt = 1.0f / fmaxf(sqrtf(sy2), 1e-12f);

    uint2 pc, pt;
    pc.x = bfbits(xc.x * inv_nc) | (bfbits(xc.y * inv_nc) << 16);
    pc.y = bfbits(xc.z * inv_nc) | (bfbits(xc.w * inv_nc) << 16);
    pt.x = bfbits(xt.x * inv_nt) | (bfbits(xt.y * inv_nt) << 16);
    pt.y = bfbits(xt.z * inv_nt) | (bfbits(xt.w * inv_nt) << 16);
    ((uint2*)(cnb + row * DDIM))[lane] = pc;
    ((uint2*)(tnb + row * DDIM))[lane] = pt;

    if (lane == 0) atomicAdd(&accum[0], dsq);
}

// ---------------------------------------------------------------------------
// Kernel 1b: DFT basis, transposed layout basisT[288][256] bf16.
// rows 0..128   : cos(2*pi*n*k/256)  (bin n)
// rows 144..272 : sin(2*pi*(n-144)*k/256)  (bin n-144; sign irrelevant for mag)
// other rows zero. Frag-aligned: bin k's cos is frag nc=k/16, sin frag nc+9,
// SAME lane (k&15).
// ---------------------------------------------------------------------------
__global__ __launch_bounds__(256) void k_basis(unsigned short* __restrict__ basisT) {
    const int n = blockIdx.x;    // 0..287
    const int k = threadIdx.x;   // 0..255
    float v = 0.0f;
    const float step = 0.0245436926f;  // 2*pi/256
    if (n < 129)                 v = cosf(step * (float)((n * k) & 255));
    else if (n >= 144 && n < 273) v = sinf(step * (float)(((n - 144) * k) & 255));
    basisT[n * DDIM + k] = (unsigned short)bfbits(v);
}

// ---------------------------------------------------------------------------
// Kernel 2: DFT-as-MFMA + frequency MSE. Block = 4 waves; waves 0,1 do 32
// clean rows, waves 2,3 the SAME 32 turb rows. Each wave: 16 rows x 288 cols,
// A-frags from global fp32 (converted), B-frags from L2-resident basisT.
// Magnitudes exchanged through LDS; block reduces (mc-mt)^2.
// ---------------------------------------------------------------------------
#define NF 18
__global__ __launch_bounds__(256) void k_dft(const float* __restrict__ clean,
                                             const float* __restrict__ turb,
                                             const unsigned short* __restrict__ basisT,
                                             float* __restrict__ accum) {
    __shared__ float mag[64][132];   // rows 0..31 clean, 32..63 turb
    __shared__ float rbuf[4];

    const int w    = threadIdx.x >> 6;
    const int lane = threadIdx.x & 63;
    const int rb   = blockIdx.x * 32 + (w & 1) * 16;   // global row base for this wave
    const float* src = (w >> 1) ? turb : clean;

    // load + convert A fragments (8 K-chunks of 32)
    bf16x8 a[8];
    const float* rowp = src + (rb + (lane & 15)) * DDIM + ((lane >> 4) << 3);
#pragma unroll
    for (int kk = 0; kk < 8; ++kk) {
        const float4 lo = *(const float4*)(rowp + kk * 32);
        const float4 hi = *(const float4*)(rowp + kk * 32 + 4);
        bf16x8 t;
        t[0] = (short)bfbits(lo.x); t[1] = (short)bfbits(lo.y);
        t[2] = (short)bfbits(lo.z); t[3] = (short)bfbits(lo.w);
        t[4] = (short)bfbits(hi.x); t[5] = (short)bfbits(hi.y);
        t[6] = (short)bfbits(hi.z); t[7] = (short)bfbits(hi.w);
        a[kk] = t;
    }

    f32x4 acc[NF];
#pragma unroll
    for (int n = 0; n < NF; ++n) acc[n] = (f32x4){0.f, 0.f, 0.f, 0.f};

    const unsigned short* bbase = basisT + (lane & 15) * DDIM + ((lane >> 4) << 3);
#pragma unroll
    for (int n = 0; n < NF; ++n) {
#pragma unroll
        for (int kk = 0; kk < 8; ++kk) {
            bf16x8 b = *(const bf16x8*)(bbase + n * 16 * DDIM + kk * 32);
            acc[n] = __builtin_amdgcn_mfma_f32_16x16x32_bf16(a[kk], b, acc[n], 0, 0, 0);
        }
    }

    // magnitudes -> LDS.  C/D layout: col=lane&15, row=(lane>>4)*4+r
    const int lrow = (w & 1) * 16 + ((lane >> 4) << 2);  // row within 32-row block
    const int half = (w >> 1) * 32;                      // clean at 0, turb at 32
#pragma unroll
    for (int nc = 0; nc < 9; ++nc) {
        const int bin = nc * 16 + (lane & 15);
        if (bin <= 128) {
#pragma unroll
            for (int r = 0; r < 4; ++r) {
                const float cr = acc[nc][r];
                const float ci = acc[nc + 9][r];
                mag[half + lrow + r][bin] = sqrtf(cr * cr + ci * ci);
            }
        }
    }
    __syncthreads();

    // block-wide reduce of (mc - mt)^2 over 32 rows x 129 bins
    float s = 0.0f;
    for (int i = threadIdx.x; i < 32 * NBINS; i += 256) {
        const int r = i / NBINS;
        const int b = i - r * NBINS;
        const float d = mag[r][b] - mag[32 + r][b];
        s += d * d;
    }
    s = wave_red(s);
    if (lane == 0) rbuf[w] = s;
    __syncthreads();
    if (threadIdx.x == 0)
        atomicAdd(&accum[1], rbuf[0] + rbuf[1] + rbuf[2] + rbuf[3]);
}

// ---------------------------------------------------------------------------
// Kernel 3: 128x128 bf16 MFMA GEMM (m97 structure: global_load_lds width 16,
// linear LDS, 2-barrier K-loop) fused with exp + label mask + per-row sums.
// ---------------------------------------------------------------------------
#define BM 128
#define BN 128
#define BK 64

__global__ __launch_bounds__(256) void k_gemm(const unsigned short* __restrict__ cnb,
                                              const unsigned short* __restrict__ tnb,
                                              const int* __restrict__ sid,
                                              float* __restrict__ all_sum,
                                              float* __restrict__ pos_sum) {
    __shared__ unsigned short As[BM][BK];
    __shared__ unsigned short Bs[BN][BK];
    __shared__ int sidI[BM], sidJ[BN];

    const int t  = threadIdx.x;
    const int i0 = blockIdx.y * BM;
    const int j0 = blockIdx.x * BN;

    if (t < 128) sidI[t] = sid[i0 + t];
    else         sidJ[t - 128] = sid[j0 + t - 128];

    const int wid  = t >> 6;
    const int lane = t & 63;
    const int wrow = (wid >> 1) * 64;
    const int wcol = (wid & 1) * 64;

    f32x4 acc[4][4];
#pragma unroll
    for (int m = 0; m < 4; ++m)
#pragma unroll
        for (int n = 0; n < 4; ++n)
            acc[m][n] = (f32x4){0.f, 0.f, 0.f, 0.f};

    for (int kt = 0; kt < DDIM / BK; ++kt) {
        if (kt) __syncthreads();
#pragma unroll
        for (int it = 0; it < 4; ++it) {
            const int idx = (it * 256 + t) * 8;   // linear element in 128x64 tile
            const int r = idx >> 6;
            const int k = idx & 63;
            gload_lds16(cnb + (i0 + r) * DDIM + kt * BK + k, &As[0][0] + idx);
            gload_lds16(tnb + (j0 + r) * DDIM + kt * BK + k, &Bs[0][0] + idx);
        }
        __syncthreads();
#pragma unroll
        for (int kk = 0; kk < BK / 32; ++kk) {
            const int kb = kk * 32 + (lane >> 4) * 8;
            bf16x8 af[4], bfr[4];
#pragma unroll
            for (int m = 0; m < 4; ++m)
                af[m] = *(const bf16x8*)&As[wrow + m * 16 + (lane & 15)][kb];
#pragma unroll
            for (int n = 0; n < 4; ++n)
                bfr[n] = *(const bf16x8*)&Bs[wcol + n * 16 + (lane & 15)][kb];
#pragma unroll
            for (int m = 0; m < 4; ++m)
#pragma unroll
                for (int n = 0; n < 4; ++n)
                    acc[m][n] = __builtin_amdgcn_mfma_f32_16x16x32_bf16(
                        af[m], bfr[n], acc[m][n], 0, 0, 0);
        }
    }

    // epilogue: exp, mask, row-reduce, atomic accumulate
    const float invT = 1.0f / 0.07f;
#pragma unroll
    for (int m = 0; m < 4; ++m) {
        const int rbase = wrow + m * 16 + ((lane >> 4) << 2);
        int si[4];
#pragma unroll
        for (int r = 0; r < 4; ++r) si[r] = sidI[rbase + r];
        float rs_all[4] = {0.f, 0.f, 0.f, 0.f};
        float rs_pos[4] = {0.f, 0.f, 0.f, 0.f};
#pragma unroll
        for (int n = 0; n < 4; ++n) {
            const int col = wcol + n * 16 + (lane & 15);
            const int sj = sidJ[col];
#pragma unroll
            for (int r = 0; r < 4; ++r) {
                float e = __expf(acc[m][n][r] * invT);
                rs_all[r] += e;
                rs_pos[r] += (si[r] == sj) ? e : 0.0f;
            }
        }
#pragma unroll
        for (int msk = 1; msk < 16; msk <<= 1) {
#pragma unroll
            for (int r = 0; r < 4; ++r) {
                rs_all[r] += __shfl_xor(rs_all[r], msk, 64);
                rs_pos[r] += __shfl_xor(rs_pos[r], msk, 64);
            }
        }
        if ((lane & 15) == 0) {
#pragma unroll
            for (int r = 0; r < 4; ++r) {
                atomicAdd(&all_sum[i0 + rbase + r], rs_all[r]);
                atomicAdd(&pos_sum[i0 + rbase + r], rs_pos[r]);
            }
        }
    }
}

// ---------------------------------------------------------------------------
// Kernel 4: final reduction -> 4 outputs
// ---------------------------------------------------------------------------
__global__ __launch_bounds__(256) void k_final(const float* __restrict__ all_sum,
                                               const float* __restrict__ pos_sum,
                                               const float* __restrict__ accum,
                                               float* __restrict__ out) {
    __shared__ float red[256];
    float c = 0.0f;
    for (int i = threadIdx.x; i < NROWS; i += 256) {
        c += logf(all_sum[i] + 1e-8f) - logf(pos_sum[i]);
    }
    red[threadIdx.x] = c;
    __syncthreads();
#pragma unroll
    for (int s = 128; s > 0; s >>= 1) {
        if (threadIdx.x < s) red[threadIdx.x] += red[threadIdx.x + s];
        __syncthreads();
    }
    if (threadIdx.x == 0) {
        float contrastive = red[0] / (float)NROWS;
        float spatial = accum[0] / (float)(NROWS * DDIM);
        float frequency = accum[1] / (float)(NROWS * NBINS);
        float total = spatial + frequency + 0.5f * contrastive;
        out[0] = total;
        out[1] = spatial;
        out[2] = frequency;
        out[3] = contrastive;
    }
}

// ---------------------------------------------------------------------------
extern "C" void kernel_launch(void* const* d_in, const int* in_sizes, int n_in,
                              void* d_out, int out_size, void* d_ws, size_t ws_size,
                              hipStream_t stream) {
    const float* clean = (const float*)d_in[0];
    const float* turb  = (const float*)d_in[1];
    const int*   sids  = (const int*)d_in[2];

    char* ws = (char*)d_ws;
    unsigned short* cnb    = (unsigned short*)ws;                    // 4 MB
    unsigned short* tnb    = (unsigned short*)(ws + 4194304);        // 4 MB
    unsigned short* basisT = (unsigned short*)(ws + 8388608);        // 144 KB
    float* all_sum = (float*)(ws + 8650752);                         // 32 KB
    float* pos_sum = (float*)(ws + 8650752 + 32768);                 // 32 KB
    float* accum   = (float*)(ws + 8650752 + 65536);                 // 8 B

    hipMemsetAsync(ws + 8650752, 0, 65536 + 64, stream);

    hipLaunchKernelGGL(k_basis, dim3(288), dim3(256), 0, stream, basisT);
    hipLaunchKernelGGL(k_row, dim3(NROWS / 4), dim3(256), 0, stream,
                       clean, turb, cnb, tnb, accum);
    hipLaunchKernelGGL(k_dft, dim3(NROWS / 32), dim3(256), 0, stream,
                       clean, turb, basisT, accum);
    hipLaunchKernelGGL(k_gemm, dim3(NROWS / BN, NROWS / BM), dim3(256), 0, stream,
                       cnb, tnb, sids, all_sum, pos_sum);
    hipLaunchKernelGGL(k_final, dim3(1), dim3(256), 0, stream,
                       all_sum, pos_sum, accum, (float*)d_out);
}

// Round 3
// 297.957 us; speedup vs baseline: 1.3652x; 1.1023x over previous
//
#include <hip/hip_runtime.h>

#define NROWS 8192
#define DDIM  256
#define NBINS 129

typedef float f32x4 __attribute__((ext_vector_type(4)));
typedef short bf16x8 __attribute__((ext_vector_type(8)));

__device__ __forceinline__ float wave_red(float v) {
#pragma unroll
    for (int m = 32; m; m >>= 1) v += __shfl_xor(v, m, 64);
    return v;
}

__device__ __forceinline__ unsigned bfbits(float f) {
    union { float f; unsigned u; } v; v.f = f;
    return (v.u + 0x7FFFu + ((v.u >> 16) & 1u)) >> 16;
}

__device__ __forceinline__ void gload_lds16(const void* g, void* l) {
    __builtin_amdgcn_global_load_lds((const __attribute__((address_space(1))) void*)g,
                                     (__attribute__((address_space(3))) void*)l,
                                     16, 0, 0);
}

// ---------------------------------------------------------------------------
// Kernel 1: streaming per-row pass — spatial MSE partial, L2 norms,
// normalized bf16 write. One wave per row.
// ---------------------------------------------------------------------------
__global__ __launch_bounds__(256) void k_row(const float* __restrict__ clean,
                                             const float* __restrict__ turb,
                                             unsigned short* __restrict__ cnb,
                                             unsigned short* __restrict__ tnb,
                                             float* __restrict__ accum) {
    const int wid  = threadIdx.x >> 6;
    const int lane = threadIdx.x & 63;
    const int row  = blockIdx.x * 4 + wid;

    const float4 xc = ((const float4*)(clean + row * DDIM))[lane];
    const float4 xt = ((const float4*)(turb  + row * DDIM))[lane];

    float dsq = (xc.x - xt.x) * (xc.x - xt.x) + (xc.y - xt.y) * (xc.y - xt.y)
              + (xc.z - xt.z) * (xc.z - xt.z) + (xc.w - xt.w) * (xc.w - xt.w);
    float sx2 = xc.x * xc.x + xc.y * xc.y + xc.z * xc.z + xc.w * xc.w;
    float sy2 = xt.x * xt.x + xt.y * xt.y + xt.z * xt.z + xt.w * xt.w;

    dsq = wave_red(dsq);
    sx2 = wave_red(sx2);
    sy2 = wave_red(sy2);

    const float inv_nc = 1.0f / fmaxf(sqrtf(sx2), 1e-12f);
    const float inv_nt = 1.0f / fmaxf(sqrtf(sy2), 1e-12f);

    uint2 pc, pt;
    pc.x = bfbits(xc.x * inv_nc) | (bfbits(xc.y * inv_nc) << 16);
    pc.y = bfbits(xc.z * inv_nc) | (bfbits(xc.w * inv_nc) << 16);
    pt.x = bfbits(xt.x * inv_nt) | (bfbits(xt.y * inv_nt) << 16);
    pt.y = bfbits(xt.z * inv_nt) | (bfbits(xt.w * inv_nt) << 16);
    ((uint2*)(cnb + row * DDIM))[lane] = pc;
    ((uint2*)(tnb + row * DDIM))[lane] = pt;

    if (lane == 0) atomicAdd(&accum[0], dsq);
}

// ---------------------------------------------------------------------------
// Kernel 1b: DFT basis, transposed layout basisT[288][256] bf16.
// rows 0..128: cos(2*pi*n*k/256); rows 144..272: sin(...); others zero.
// ---------------------------------------------------------------------------
__global__ __launch_bounds__(256) void k_basis(unsigned short* __restrict__ basisT) {
    const int n = blockIdx.x;    // 0..287
    const int k = threadIdx.x;   // 0..255
    float v = 0.0f;
    const float step = 0.0245436926f;  // 2*pi/256
    if (n < 129)                  v = cosf(step * (float)((n * k) & 255));
    else if (n >= 144 && n < 273) v = sinf(step * (float)(((n - 144) * k) & 255));
    basisT[n * DDIM + k] = (unsigned short)bfbits(v);
}

// ---------------------------------------------------------------------------
// Kernel 2: DFT-as-MFMA + frequency MSE.
// Block = 4 waves over the SAME 16 rows; wave = {clean,turb} x {cos,sin}.
// Each wave: 9 frags x 8 kk = 72 MFMAs, 9 f32x4 accs (low reg pressure).
// Grid = 512 blocks -> 2 blocks/CU, 8 waves/CU.
// ---------------------------------------------------------------------------
__global__ __launch_bounds__(256) void k_dft(const float* __restrict__ clean,
                                             const float* __restrict__ turb,
                                             const unsigned short* __restrict__ basisT,
                                             float* __restrict__ accum) {
    __shared__ float xch[2][2][16][132];   // [src][trig][row][bin]
    __shared__ float rbuf[4];

    const int w    = threadIdx.x >> 6;
    const int lane = threadIdx.x & 63;
    const int srcw = w & 1;
    const int trig = w >> 1;
    const int rb   = blockIdx.x * 16;
    const float* src = srcw ? turb : clean;

    // load + convert this wave's A fragments (16 rows x 256 cols, frag layout)
    bf16x8 a[8];
    const float* rowp = src + (rb + (lane & 15)) * DDIM + ((lane >> 4) << 3);
#pragma unroll
    for (int kk = 0; kk < 8; ++kk) {
        const float4 lo = *(const float4*)(rowp + kk * 32);
        const float4 hi = *(const float4*)(rowp + kk * 32 + 4);
        bf16x8 tv;
        tv[0] = (short)bfbits(lo.x); tv[1] = (short)bfbits(lo.y);
        tv[2] = (short)bfbits(lo.z); tv[3] = (short)bfbits(lo.w);
        tv[4] = (short)bfbits(hi.x); tv[5] = (short)bfbits(hi.y);
        tv[6] = (short)bfbits(hi.z); tv[7] = (short)bfbits(hi.w);
        a[kk] = tv;
    }

    f32x4 acc[9];
#pragma unroll
    for (int n = 0; n < 9; ++n) acc[n] = (f32x4){0.f, 0.f, 0.f, 0.f};

    const unsigned short* bbase = basisT + (trig * 144 + (lane & 15)) * DDIM
                                + ((lane >> 4) << 3);
#pragma unroll
    for (int n = 0; n < 9; ++n) {
#pragma unroll
        for (int kk = 0; kk < 8; ++kk) {
            bf16x8 b = *(const bf16x8*)(bbase + n * 16 * DDIM + kk * 32);
            acc[n] = __builtin_amdgcn_mfma_f32_16x16x32_bf16(a[kk], b, acc[n], 0, 0, 0);
        }
    }

    // C/D layout: col(bin)=lane&15, row=(lane>>4)*4+r
    const int lrow = (lane >> 4) << 2;
#pragma unroll
    for (int nc = 0; nc < 9; ++nc) {
        const int bin = nc * 16 + (lane & 15);
        if (bin < NBINS) {
#pragma unroll
            for (int r = 0; r < 4; ++r)
                xch[srcw][trig][lrow + r][bin] = acc[nc][r];
        }
    }
    __syncthreads();

    // block reduce of (|fft_c| - |fft_t|)^2 over 16 rows x 129 bins
    const int rr = threadIdx.x >> 4;
    float s = 0.0f;
    for (int b = (threadIdx.x & 15); b < NBINS; b += 16) {
        const float crc = xch[0][0][rr][b], cic = xch[0][1][rr][b];
        const float crt = xch[1][0][rr][b], cit = xch[1][1][rr][b];
        const float d = sqrtf(crc * crc + cic * cic) - sqrtf(crt * crt + cit * cit);
        s += d * d;
    }
    s = wave_red(s);
    if (lane == 0) rbuf[w] = s;
    __syncthreads();
    if (threadIdx.x == 0)
        atomicAdd(&accum[1], rbuf[0] + rbuf[1] + rbuf[2] + rbuf[3]);
}

// ---------------------------------------------------------------------------
// Kernel 3: 128x128 bf16 MFMA GEMM, T2 XOR-swizzled LDS via pre-swizzled
// global source (linear gload_lds dest + swizzled ds_read), fused epilogue.
// Swizzle: 16B-slot index s at row r holds source slot s^(r&7).
// ---------------------------------------------------------------------------
#define BM 128
#define BN 128
#define BK 64

__global__ __launch_bounds__(256) void k_gemm(const unsigned short* __restrict__ cnb,
                                              const unsigned short* __restrict__ tnb,
                                              const int* __restrict__ sid,
                                              float* __restrict__ all_sum,
                                              float* __restrict__ pos_sum) {
    __shared__ unsigned short As[BM][BK];
    __shared__ unsigned short Bs[BN][BK];
    __shared__ int sidI[BM], sidJ[BN];

    const int t  = threadIdx.x;
    const int i0 = blockIdx.y * BM;
    const int j0 = blockIdx.x * BN;

    if (t < 128) sidI[t] = sid[i0 + t];
    else         sidJ[t - 128] = sid[j0 + t - 128];

    const int wid  = t >> 6;
    const int lane = t & 63;
    const int wrow = (wid >> 1) * 64;
    const int wcol = (wid & 1) * 64;
    const int rx   = lane & 7;           // read-side XOR value (row&7)

    f32x4 acc[4][4];
#pragma unroll
    for (int m = 0; m < 4; ++m)
#pragma unroll
        for (int n = 0; n < 4; ++n)
            acc[m][n] = (f32x4){0.f, 0.f, 0.f, 0.f};

    for (int kt = 0; kt < DDIM / BK; ++kt) {
        if (kt) __syncthreads();
        // stage: linear LDS dest, inverse-swizzled global source
#pragma unroll
        for (int it = 0; it < 4; ++it) {
            const int g  = it * 256 + t;          // 16B granule 0..1023
            const int r  = g >> 3;                // tile row
            const int sl = g & 7;                 // dest slot within row
            const int sc = ((sl ^ (r & 7)) << 3); // source col (elements)
            gload_lds16(cnb + (i0 + r) * DDIM + kt * BK + sc,
                        (char*)&As[0][0] + g * 16);
            gload_lds16(tnb + (j0 + r) * DDIM + kt * BK + sc,
                        (char*)&Bs[0][0] + g * 16);
        }
        __syncthreads();
#pragma unroll
        for (int kk = 0; kk < BK / 32; ++kk) {
            const int kslot = kk * 4 + (lane >> 4);   // 16B slot of the frag
            bf16x8 af[4], bfr[4];
#pragma unroll
            for (int m = 0; m < 4; ++m) {
                const int row = wrow + m * 16 + (lane & 15);
                af[m] = *(const bf16x8*)((const char*)&As[0][0]
                          + row * 128 + ((kslot ^ rx) << 4));
            }
#pragma unroll
            for (int n = 0; n < 4; ++n) {
                const int row = wcol + n * 16 + (lane & 15);
                bfr[n] = *(const bf16x8*)((const char*)&Bs[0][0]
                          + row * 128 + ((kslot ^ rx) << 4));
            }
#pragma unroll
            for (int m = 0; m < 4; ++m)
#pragma unroll
                for (int n = 0; n < 4; ++n)
                    acc[m][n] = __builtin_amdgcn_mfma_f32_16x16x32_bf16(
                        af[m], bfr[n], acc[m][n], 0, 0, 0);
        }
    }

    // epilogue: exp, mask, row-reduce, atomic accumulate
    const float invT = 1.0f / 0.07f;
#pragma unroll
    for (int m = 0; m < 4; ++m) {
        const int rbase = wrow + m * 16 + ((lane >> 4) << 2);
        int si[4];
#pragma unroll
        for (int r = 0; r < 4; ++r) si[r] = sidI[rbase + r];
        float rs_all[4] = {0.f, 0.f, 0.f, 0.f};
        float rs_pos[4] = {0.f, 0.f, 0.f, 0.f};
#pragma unroll
        for (int n = 0; n < 4; ++n) {
            const int col = wcol + n * 16 + (lane & 15);
            const int sj = sidJ[col];
#pragma unroll
            for (int r = 0; r < 4; ++r) {
                float e = __expf(acc[m][n][r] * invT);
                rs_all[r] += e;
                rs_pos[r] += (si[r] == sj) ? e : 0.0f;
            }
        }
#pragma unroll
        for (int msk = 1; msk < 16; msk <<= 1) {
#pragma unroll
            for (int r = 0; r < 4; ++r) {
                rs_all[r] += __shfl_xor(rs_all[r], msk, 64);
                rs_pos[r] += __shfl_xor(rs_pos[r], msk, 64);
            }
        }
        if ((lane & 15) == 0) {
#pragma unroll
            for (int r = 0; r < 4; ++r) {
                atomicAdd(&all_sum[i0 + rbase + r], rs_all[r]);
                atomicAdd(&pos_sum[i0 + rbase + r], rs_pos[r]);
            }
        }
    }
}

// ---------------------------------------------------------------------------
// Kernel 4: final reduction -> 4 outputs
// ---------------------------------------------------------------------------
__global__ __launch_bounds__(256) void k_final(const float* __restrict__ all_sum,
                                               const float* __restrict__ pos_sum,
                                               const float* __restrict__ accum,
                                               float* __restrict__ out) {
    __shared__ float red[256];
    float c = 0.0f;
    for (int i = threadIdx.x; i < NROWS; i += 256) {
        c += logf(all_sum[i] + 1e-8f) - logf(pos_sum[i]);
    }
    red[threadIdx.x] = c;
    __syncthreads();
#pragma unroll
    for (int s = 128; s > 0; s >>= 1) {
        if (threadIdx.x < s) red[threadIdx.x] += red[threadIdx.x + s];
        __syncthreads();
    }
    if (threadIdx.x == 0) {
        float contrastive = red[0] / (float)NROWS;
        float spatial = accum[0] / (float)(NROWS * DDIM);
        float frequency = accum[1] / (float)(NROWS * NBINS);
        float total = spatial + frequency + 0.5f * contrastive;
        out[0] = total;
        out[1] = spatial;
        out[2] = frequency;
        out[3] = contrastive;
    }
}

// ---------------------------------------------------------------------------
extern "C" void kernel_launch(void* const* d_in, const int* in_sizes, int n_in,
                              void* d_out, int out_size, void* d_ws, size_t ws_size,
                              hipStream_t stream) {
    const float* clean = (const float*)d_in[0];
    const float* turb  = (const float*)d_in[1];
    const int*   sids  = (const int*)d_in[2];

    char* ws = (char*)d_ws;
    unsigned short* cnb    = (unsigned short*)ws;                    // 4 MB
    unsigned short* tnb    = (unsigned short*)(ws + 4194304);        // 4 MB
    unsigned short* basisT = (unsigned short*)(ws + 8388608);        // 144 KB
    float* all_sum = (float*)(ws + 8650752);                         // 32 KB
    float* pos_sum = (float*)(ws + 8650752 + 32768);                 // 32 KB
    float* accum   = (float*)(ws + 8650752 + 65536);                 // 8 B

    hipMemsetAsync(ws + 8650752, 0, 65536 + 64, stream);

    hipLaunchKernelGGL(k_basis, dim3(288), dim3(256), 0, stream, basisT);
    hipLaunchKernelGGL(k_row, dim3(NROWS / 4), dim3(256), 0, stream,
                       clean, turb, cnb, tnb, accum);
    hipLaunchKernelGGL(k_dft, dim3(NROWS / 16), dim3(256), 0, stream,
                       clean, turb, basisT, accum);
    hipLaunchKernelGGL(k_gemm, dim3(NROWS / BN, NROWS / BM), dim3(256), 0, stream,
                       cnb, tnb, sids, all_sum, pos_sum);
    hipLaunchKernelGGL(k_final, dim3(1), dim3(256), 0, stream,
                       all_sum, pos_sum, accum, (float*)d_out);
}

// Round 4
// 114.756 us; speedup vs baseline: 3.5447x; 2.5964x over previous
//
#include <hip/hip_runtime.h>

#define NROWS 8192
#define DDIM  256
#define NBINS 129

typedef float f32x4 __attribute__((ext_vector_type(4)));
typedef short bf16x8 __attribute__((ext_vector_type(8)));

__device__ __forceinline__ float wave_red(float v) {
#pragma unroll
    for (int m = 32; m; m >>= 1) v += __shfl_xor(v, m, 64);
    return v;
}

__device__ __forceinline__ unsigned bfbits(float f) {
    union { float f; unsigned u; } v; v.f = f;
    return (v.u + 0x7FFFu + ((v.u >> 16) & 1u)) >> 16;
}

__device__ __forceinline__ void gload_lds16(const void* g, void* l) {
    __builtin_amdgcn_global_load_lds((const __attribute__((address_space(1))) void*)g,
                                     (__attribute__((address_space(3))) void*)l,
                                     16, 0, 0);
}

// ---------------------------------------------------------------------------
// Kernel 1: streaming per-row pass — spatial MSE partial (per-block store,
// NO atomics), L2 norms, normalized bf16 write.
// ---------------------------------------------------------------------------
__global__ __launch_bounds__(256) void k_row(const float* __restrict__ clean,
                                             const float* __restrict__ turb,
                                             unsigned short* __restrict__ cnb,
                                             unsigned short* __restrict__ tnb,
                                             float* __restrict__ spat_part) {
    __shared__ float sp4[4];
    const int wid  = threadIdx.x >> 6;
    const int lane = threadIdx.x & 63;
    const int row  = blockIdx.x * 4 + wid;

    const float4 xc = ((const float4*)(clean + row * DDIM))[lane];
    const float4 xt = ((const float4*)(turb  + row * DDIM))[lane];

    float dsq = (xc.x - xt.x) * (xc.x - xt.x) + (xc.y - xt.y) * (xc.y - xt.y)
              + (xc.z - xt.z) * (xc.z - xt.z) + (xc.w - xt.w) * (xc.w - xt.w);
    float sx2 = xc.x * xc.x + xc.y * xc.y + xc.z * xc.z + xc.w * xc.w;
    float sy2 = xt.x * xt.x + xt.y * xt.y + xt.z * xt.z + xt.w * xt.w;

    dsq = wave_red(dsq);
    sx2 = wave_red(sx2);
    sy2 = wave_red(sy2);

    const float inv_nc = 1.0f / fmaxf(sqrtf(sx2), 1e-12f);
    const float inv_nt = 1.0f / fmaxf(sqrtf(sy2), 1e-12f);

    uint2 pc, pt;
    pc.x = bfbits(xc.x * inv_nc) | (bfbits(xc.y * inv_nc) << 16);
    pc.y = bfbits(xc.z * inv_nc) | (bfbits(xc.w * inv_nc) << 16);
    pt.x = bfbits(xt.x * inv_nt) | (bfbits(xt.y * inv_nt) << 16);
    pt.y = bfbits(xt.z * inv_nt) | (bfbits(xt.w * inv_nt) << 16);
    ((uint2*)(cnb + row * DDIM))[lane] = pc;
    ((uint2*)(tnb + row * DDIM))[lane] = pt;

    if (lane == 0) sp4[wid] = dsq;
    __syncthreads();
    if (threadIdx.x == 0)
        spat_part[blockIdx.x] = sp4[0] + sp4[1] + sp4[2] + sp4[3];
}

// ---------------------------------------------------------------------------
// Kernel 1b: DFT basis, transposed layout basisT[288][256] bf16.
// ---------------------------------------------------------------------------
__global__ __launch_bounds__(256) void k_basis(unsigned short* __restrict__ basisT) {
    const int n = blockIdx.x;    // 0..287
    const int k = threadIdx.x;   // 0..255
    float v = 0.0f;
    const float step = 0.0245436926f;  // 2*pi/256
    if (n < 129)                  v = cosf(step * (float)((n * k) & 255));
    else if (n >= 144 && n < 273) v = sinf(step * (float)(((n - 144) * k) & 255));
    basisT[n * DDIM + k] = (unsigned short)bfbits(v);
}

// ---------------------------------------------------------------------------
// Kernel 2: DFT-as-MFMA + frequency MSE. Per-block partial store, NO atomics.
// n-loop unroll-capped to bound in-flight loads / registers.
// ---------------------------------------------------------------------------
__global__ __launch_bounds__(256) void k_dft(const float* __restrict__ clean,
                                             const float* __restrict__ turb,
                                             const unsigned short* __restrict__ basisT,
                                             float* __restrict__ freq_part) {
    __shared__ float xch[2][2][16][132];   // [src][trig][row][bin]
    __shared__ float rbuf[4];

    const int w    = threadIdx.x >> 6;
    const int lane = threadIdx.x & 63;
    const int srcw = w & 1;
    const int trig = w >> 1;
    const int rb   = blockIdx.x * 16;
    const float* src = srcw ? turb : clean;

    bf16x8 a[8];
    const float* rowp = src + (rb + (lane & 15)) * DDIM + ((lane >> 4) << 3);
#pragma unroll
    for (int kk = 0; kk < 8; ++kk) {
        const float4 lo = *(const float4*)(rowp + kk * 32);
        const float4 hi = *(const float4*)(rowp + kk * 32 + 4);
        bf16x8 tv;
        tv[0] = (short)bfbits(lo.x); tv[1] = (short)bfbits(lo.y);
        tv[2] = (short)bfbits(lo.z); tv[3] = (short)bfbits(lo.w);
        tv[4] = (short)bfbits(hi.x); tv[5] = (short)bfbits(hi.y);
        tv[6] = (short)bfbits(hi.z); tv[7] = (short)bfbits(hi.w);
        a[kk] = tv;
    }

    const unsigned short* bbase = basisT + (trig * 144 + (lane & 15)) * DDIM
                                + ((lane >> 4) << 3);
    const int lrow = (lane >> 4) << 2;

#pragma unroll 1
    for (int n = 0; n < 9; ++n) {
        f32x4 acc = (f32x4){0.f, 0.f, 0.f, 0.f};
#pragma unroll
        for (int kk = 0; kk < 8; ++kk) {
            bf16x8 b = *(const bf16x8*)(bbase + n * 16 * DDIM + kk * 32);
            acc = __builtin_amdgcn_mfma_f32_16x16x32_bf16(a[kk], b, acc, 0, 0, 0);
        }
        const int bin = n * 16 + (lane & 15);
        if (bin < 132) {   // write all; reduce loop only reads < NBINS
#pragma unroll
            for (int r = 0; r < 4; ++r)
                xch[srcw][trig][lrow + r][bin] = acc[r];
        }
    }
    __syncthreads();

    // block reduce of (|fft_c| - |fft_t|)^2 over 16 rows x 129 bins
    const int rr = threadIdx.x >> 4;
    float s = 0.0f;
    for (int b = (threadIdx.x & 15); b < NBINS; b += 16) {
        const float crc = xch[0][0][rr][b], cic = xch[0][1][rr][b];
        const float crt = xch[1][0][rr][b], cit = xch[1][1][rr][b];
        const float d = sqrtf(crc * crc + cic * cic) - sqrtf(crt * crt + cit * cit);
        s += d * d;
    }
    s = wave_red(s);
    if (lane == 0) rbuf[w] = s;
    __syncthreads();
    if (threadIdx.x == 0)
        freq_part[blockIdx.x] = rbuf[0] + rbuf[1] + rbuf[2] + rbuf[3];
}

// ---------------------------------------------------------------------------
// Kernel 3: 128x128 bf16 MFMA GEMM, double-buffered LDS (2-phase overlap),
// swizzled staging, fused exp/mask epilogue -> per-block partial STORES.
// ---------------------------------------------------------------------------
#define BM 128
#define BN 128
#define BK 64

__global__ __launch_bounds__(256) void k_gemm(const unsigned short* __restrict__ cnb,
                                              const unsigned short* __restrict__ tnb,
                                              const int* __restrict__ sid,
                                              float* __restrict__ pall,
                                              float* __restrict__ ppos) {
    __shared__ unsigned short As[2][BM][BK];
    __shared__ unsigned short Bs[2][BN][BK];
    __shared__ float ps[2][BM][2];          // [colhalf][row][all|pos]
    __shared__ int sidI[BM], sidJ[BN];

    const int t  = threadIdx.x;
    const int i0 = blockIdx.y * BM;
    const int j0 = blockIdx.x * BN;

    if (t < 128) sidI[t] = sid[i0 + t];
    else         sidJ[t - 128] = sid[j0 + t - 128];

    const int wid  = t >> 6;
    const int lane = t & 63;
    const int wrow = (wid >> 1) * 64;
    const int wcol = (wid & 1) * 64;
    const int rx   = lane & 7;

    f32x4 acc[4][4];
#pragma unroll
    for (int m = 0; m < 4; ++m)
#pragma unroll
        for (int n = 0; n < 4; ++n)
            acc[m][n] = (f32x4){0.f, 0.f, 0.f, 0.f};

    // staging: linear LDS dest, inverse-swizzled global source
#define STAGE(buf, kt)                                                        \
    {                                                                         \
        _Pragma("unroll")                                                     \
        for (int it = 0; it < 4; ++it) {                                      \
            const int g  = it * 256 + t;                                      \
            const int r  = g >> 3;                                            \
            const int sl = g & 7;                                             \
            const int sc = ((sl ^ (r & 7)) << 3);                             \
            gload_lds16(cnb + (i0 + r) * DDIM + (kt) * BK + sc,               \
                        (char*)&As[buf][0][0] + g * 16);                      \
            gload_lds16(tnb + (j0 + r) * DDIM + (kt) * BK + sc,               \
                        (char*)&Bs[buf][0][0] + g * 16);                      \
        }                                                                     \
    }

    int cur = 0;
    STAGE(0, 0);
    __syncthreads();

    for (int kt = 0; kt < DDIM / BK; ++kt) {
        if (kt < DDIM / BK - 1) STAGE(cur ^ 1, kt + 1);
#pragma unroll
        for (int kk = 0; kk < BK / 32; ++kk) {
            const int kslot = kk * 4 + (lane >> 4);
            bf16x8 af[4], bfr[4];
#pragma unroll
            for (int m = 0; m < 4; ++m) {
                const int row = wrow + m * 16 + (lane & 15);
                af[m] = *(const bf16x8*)((const char*)&As[cur][0][0]
                          + row * 128 + ((kslot ^ rx) << 4));
            }
#pragma unroll
            for (int n = 0; n < 4; ++n) {
                const int row = wcol + n * 16 + (lane & 15);
                bfr[n] = *(const bf16x8*)((const char*)&Bs[cur][0][0]
                          + row * 128 + ((kslot ^ rx) << 4));
            }
#pragma unroll
            for (int m = 0; m < 4; ++m)
#pragma unroll
                for (int n = 0; n < 4; ++n)
                    acc[m][n] = __builtin_amdgcn_mfma_f32_16x16x32_bf16(
                        af[m], bfr[n], acc[m][n], 0, 0, 0);
        }
        __syncthreads();
        cur ^= 1;
    }
#undef STAGE

    // epilogue: exp, mask, 16-lane row-reduce, LDS combine, per-block store
    const float invT = 1.0f / 0.07f;
#pragma unroll
    for (int m = 0; m < 4; ++m) {
        const int rbase = wrow + m * 16 + ((lane >> 4) << 2);
        int si[4];
#pragma unroll
        for (int r = 0; r < 4; ++r) si[r] = sidI[rbase + r];
        float rs_all[4] = {0.f, 0.f, 0.f, 0.f};
        float rs_pos[4] = {0.f, 0.f, 0.f, 0.f};
#pragma unroll
        for (int n = 0; n < 4; ++n) {
            const int col = wcol + n * 16 + (lane & 15);
            const int sj = sidJ[col];
#pragma unroll
            for (int r = 0; r < 4; ++r) {
                float e = __expf(acc[m][n][r] * invT);
                rs_all[r] += e;
                rs_pos[r] += (si[r] == sj) ? e : 0.0f;
            }
        }
#pragma unroll
        for (int msk = 1; msk < 16; msk <<= 1) {
#pragma unroll
            for (int r = 0; r < 4; ++r) {
                rs_all[r] += __shfl_xor(rs_all[r], msk, 64);
                rs_pos[r] += __shfl_xor(rs_pos[r], msk, 64);
            }
        }
        if ((lane & 15) == 0) {
#pragma unroll
            for (int r = 0; r < 4; ++r) {
                ps[wid & 1][rbase + r][0] = rs_all[r];
                ps[wid & 1][rbase + r][1] = rs_pos[r];
            }
        }
    }
    __syncthreads();
    if (t < BM) {
        const float sa = ps[0][t][0] + ps[1][t][0];
        const float sp = ps[0][t][1] + ps[1][t][1];
        pall[blockIdx.x * NROWS + i0 + t] = sa;
        ppos[blockIdx.x * NROWS + i0 + t] = sp;
    }
}

// ---------------------------------------------------------------------------
// Kernel 4: per-row sum over 64 j-block partials + log terms -> per-block
// contrastive partial (32 blocks x 256 rows).
// ---------------------------------------------------------------------------
__global__ __launch_bounds__(256) void k_red(const float* __restrict__ pall,
                                             const float* __restrict__ ppos,
                                             float* __restrict__ contrib) {
    __shared__ float red[256];
    const int row = blockIdx.x * 256 + threadIdx.x;
    float sa = 0.0f, sp = 0.0f;
    for (int jb = 0; jb < 64; ++jb) {
        sa += pall[jb * NROWS + row];
        sp += ppos[jb * NROWS + row];
    }
    red[threadIdx.x] = logf(sa + 1e-8f) - logf(sp);
    __syncthreads();
#pragma unroll
    for (int s = 128; s > 0; s >>= 1) {
        if (threadIdx.x < s) red[threadIdx.x] += red[threadIdx.x + s];
        __syncthreads();
    }
    if (threadIdx.x == 0) contrib[blockIdx.x] = red[0];
}

// ---------------------------------------------------------------------------
// Kernel 5: fold all partials -> 4 outputs
// ---------------------------------------------------------------------------
__global__ __launch_bounds__(256) void k_final(const float* __restrict__ spat_part,
                                               const float* __restrict__ freq_part,
                                               const float* __restrict__ contrib,
                                               float* __restrict__ out) {
    __shared__ float reda[256], redb[256], redc[256];
    float a = 0.0f, b = 0.0f, c = 0.0f;
    for (int i = threadIdx.x; i < 2048; i += 256) a += spat_part[i];
    for (int i = threadIdx.x; i < 512;  i += 256) b += freq_part[i];
    if (threadIdx.x < 32) c = contrib[threadIdx.x];
    reda[threadIdx.x] = a; redb[threadIdx.x] = b; redc[threadIdx.x] = c;
    __syncthreads();
#pragma unroll
    for (int s = 128; s > 0; s >>= 1) {
        if (threadIdx.x < s) {
            reda[threadIdx.x] += reda[threadIdx.x + s];
            redb[threadIdx.x] += redb[threadIdx.x + s];
            redc[threadIdx.x] += redc[threadIdx.x + s];
        }
        __syncthreads();
    }
    if (threadIdx.x == 0) {
        float spatial = reda[0] / (float)(NROWS * DDIM);
        float frequency = redb[0] / (float)(NROWS * NBINS);
        float contrastive = redc[0] / (float)NROWS;
        out[0] = spatial + frequency + 0.5f * contrastive;
        out[1] = spatial;
        out[2] = frequency;
        out[3] = contrastive;
    }
}

// ---------------------------------------------------------------------------
extern "C" void kernel_launch(void* const* d_in, const int* in_sizes, int n_in,
                              void* d_out, int out_size, void* d_ws, size_t ws_size,
                              hipStream_t stream) {
    const float* clean = (const float*)d_in[0];
    const float* turb  = (const float*)d_in[1];
    const int*   sids  = (const int*)d_in[2];

    char* ws = (char*)d_ws;
    unsigned short* cnb    = (unsigned short*)ws;                      // 4 MB
    unsigned short* tnb    = (unsigned short*)(ws + 4194304);          // 4 MB
    unsigned short* basisT = (unsigned short*)(ws + 8388608);          // 147 KB
    float* pall      = (float*)(ws + 8650752);                         // 2 MB
    float* ppos      = (float*)(ws + 10747904);                        // 2 MB
    float* spat_part = (float*)(ws + 12845056);                        // 8 KB
    float* freq_part = (float*)(ws + 12853248);                        // 2 KB
    float* contrib   = (float*)(ws + 12855296);                        // 128 B

    hipLaunchKernelGGL(k_basis, dim3(288), dim3(256), 0, stream, basisT);
    hipLaunchKernelGGL(k_row, dim3(NROWS / 4), dim3(256), 0, stream,
                       clean, turb, cnb, tnb, spat_part);
    hipLaunchKernelGGL(k_dft, dim3(NROWS / 16), dim3(256), 0, stream,
                       clean, turb, basisT, freq_part);
    hipLaunchKernelGGL(k_gemm, dim3(NROWS / BN, NROWS / BM), dim3(256), 0, stream,
                       cnb, tnb, sids, pall, ppos);
    hipLaunchKernelGGL(k_red, dim3(NROWS / 256), dim3(256), 0, stream,
                       pall, ppos, contrib);
    hipLaunchKernelGGL(k_final, dim3(1), dim3(256), 0, stream,
                       spat_part, freq_part, contrib, (float*)d_out);
}

// Round 6
// 106.764 us; speedup vs baseline: 3.8101x; 1.0749x over previous
//
#include <hip/hip_runtime.h>

#define NROWS 8192
#define DDIM  256
#define NBINS 129

typedef float f32x4 __attribute__((ext_vector_type(4)));
typedef short bf16x8 __attribute__((ext_vector_type(8)));

__device__ __forceinline__ float wave_red(float v) {
#pragma unroll
    for (int m = 32; m; m >>= 1) v += __shfl_xor(v, m, 64);
    return v;
}

__device__ __forceinline__ unsigned bfbits(float f) {
    union { float f; unsigned u; } v; v.f = f;
    return (v.u + 0x7FFFu + ((v.u >> 16) & 1u)) >> 16;
}

__device__ __forceinline__ void gload_lds16(const void* g, void* l) {
    __builtin_amdgcn_global_load_lds((const __attribute__((address_space(1))) void*)g,
                                     (__attribute__((address_space(3))) void*)l,
                                     16, 0, 0);
}

// ---------------------------------------------------------------------------
// Kernel 1: DFT basis, transposed layout basisT[288][256] bf16.
// rows 0..128: cos(2*pi*n*k/256); rows 144..272: sin; others zero.
// ---------------------------------------------------------------------------
__global__ __launch_bounds__(256) void k_basis(unsigned short* __restrict__ basisT) {
    const int n = blockIdx.x;    // 0..287
    const int k = threadIdx.x;   // 0..255
    float v = 0.0f;
    const float step = 0.0245436926f;  // 2*pi/256
    if (n < 129)                  v = cosf(step * (float)((n * k) & 255));
    else if (n >= 144 && n < 273) v = sinf(step * (float)(((n - 144) * k) & 255));
    basisT[n * DDIM + k] = (unsigned short)bfbits(v);
}

// ---------------------------------------------------------------------------
// Kernel 2 (fused k_row + k_dft): per 16-row block —
//  phase 1: single global read of clean+turb; spatial MSE + row norms
//  phase 2: normalized bf16 write (for k_gemm)
//  phase 3: re-read rows from LDS as MFMA A-fragments
//  phase 4: DFT via MFMA against basisT, magnitudes, frequency MSE partial
// ---------------------------------------------------------------------------
__global__ __launch_bounds__(256) void k_prep(const float* __restrict__ clean,
                                              const float* __restrict__ turb,
                                              const unsigned short* __restrict__ basisT,
                                              unsigned short* __restrict__ cnb,
                                              unsigned short* __restrict__ tnb,
                                              float* __restrict__ spat_part,
                                              float* __restrict__ freq_part) {
    __shared__ float xraw[2][16][260];     // fp32 rows, padded (260%32=4 -> 2-way free)
    __shared__ float xch[2][2][16][132];   // [src][trig][row][bin] cr/ci
    __shared__ float invn[16][2];
    __shared__ float sp4[4], rbuf[4];

    const int t    = threadIdx.x;
    const int w    = t >> 6;
    const int lane = t & 63;
    const int rb   = blockIdx.x * 16;

    // ---- phase 1: load (one global pass), partials, stage to LDS ----
    const int r = t >> 4;          // row 0..15
    const int c = t & 15;          // 16-float column chunk
    float4 xc4[4], xt4[4];
    const float* pc = clean + (rb + r) * DDIM + c * 16;
    const float* pt = turb  + (rb + r) * DDIM + c * 16;
    float dsq = 0.0f, nsc = 0.0f, nst = 0.0f;
#pragma unroll
    for (int q = 0; q < 4; ++q) {
        xc4[q] = ((const float4*)pc)[q];
        xt4[q] = ((const float4*)pt)[q];
        const float4 a = xc4[q], b = xt4[q];
        dsq += (a.x - b.x) * (a.x - b.x) + (a.y - b.y) * (a.y - b.y)
             + (a.z - b.z) * (a.z - b.z) + (a.w - b.w) * (a.w - b.w);
        nsc += a.x * a.x + a.y * a.y + a.z * a.z + a.w * a.w;
        nst += b.x * b.x + b.y * b.y + b.z * b.z + b.w * b.w;
        *(float4*)&xraw[0][r][c * 16 + q * 4] = a;
        *(float4*)&xraw[1][r][c * 16 + q * 4] = b;
    }
    // reduce norms over the 16 threads of this row (contiguous lanes)
#pragma unroll
    for (int m = 1; m < 16; m <<= 1) {
        nsc += __shfl_xor(nsc, m, 64);
        nst += __shfl_xor(nst, m, 64);
    }
    if (c == 0) {
        invn[r][0] = 1.0f / fmaxf(sqrtf(nsc), 1e-12f);
        invn[r][1] = 1.0f / fmaxf(sqrtf(nst), 1e-12f);
    }
    dsq = wave_red(dsq);
    if (lane == 0) sp4[w] = dsq;
    __syncthreads();

    // ---- phase 2: normalized bf16 writes (coalesced 16B stores) ----
    {
        const float ic = invn[r][0], it = invn[r][1];
        bf16x8 oc0, oc1, ot0, ot1;
        oc0[0] = (short)bfbits(xc4[0].x * ic); oc0[1] = (short)bfbits(xc4[0].y * ic);
        oc0[2] = (short)bfbits(xc4[0].z * ic); oc0[3] = (short)bfbits(xc4[0].w * ic);
        oc0[4] = (short)bfbits(xc4[1].x * ic); oc0[5] = (short)bfbits(xc4[1].y * ic);
        oc0[6] = (short)bfbits(xc4[1].z * ic); oc0[7] = (short)bfbits(xc4[1].w * ic);
        oc1[0] = (short)bfbits(xc4[2].x * ic); oc1[1] = (short)bfbits(xc4[2].y * ic);
        oc1[2] = (short)bfbits(xc4[2].z * ic); oc1[3] = (short)bfbits(xc4[2].w * ic);
        oc1[4] = (short)bfbits(xc4[3].x * ic); oc1[5] = (short)bfbits(xc4[3].y * ic);
        oc1[6] = (short)bfbits(xc4[3].z * ic); oc1[7] = (short)bfbits(xc4[3].w * ic);
        ot0[0] = (short)bfbits(xt4[0].x * it); ot0[1] = (short)bfbits(xt4[0].y * it);
        ot0[2] = (short)bfbits(xt4[0].z * it); ot0[3] = (short)bfbits(xt4[0].w * it);
        ot0[4] = (short)bfbits(xt4[1].x * it); ot0[5] = (short)bfbits(xt4[1].y * it);
        ot0[6] = (short)bfbits(xt4[1].z * it); ot0[7] = (short)bfbits(xt4[1].w * it);
        ot1[0] = (short)bfbits(xt4[2].x * it); ot1[1] = (short)bfbits(xt4[2].y * it);
        ot1[2] = (short)bfbits(xt4[2].z * it); ot1[3] = (short)bfbits(xt4[2].w * it);
        ot1[4] = (short)bfbits(xt4[3].x * it); ot1[5] = (short)bfbits(xt4[3].y * it);
        ot1[6] = (short)bfbits(xt4[3].z * it); ot1[7] = (short)bfbits(xt4[3].w * it);
        unsigned short* dc = cnb + (rb + r) * DDIM + c * 16;
        unsigned short* dt = tnb + (rb + r) * DDIM + c * 16;
        *(bf16x8*)(dc) = oc0; *(bf16x8*)(dc + 8) = oc1;
        *(bf16x8*)(dt) = ot0; *(bf16x8*)(dt + 8) = ot1;
    }

    // ---- phase 3: A-fragments from LDS (row = lane&15, k-chunk = lane>>4) ----
    const int srcw = w & 1;         // 0 clean, 1 turb
    const int trig = w >> 1;        // 0 cos, 1 sin
    bf16x8 a[8];
    {
        const float* xr = &xraw[srcw][lane & 15][(lane >> 4) << 3];
#pragma unroll
        for (int kk = 0; kk < 8; ++kk) {
            const float4 lo = *(const float4*)(xr + kk * 32);
            const float4 hi = *(const float4*)(xr + kk * 32 + 4);
            bf16x8 tv;
            tv[0] = (short)bfbits(lo.x); tv[1] = (short)bfbits(lo.y);
            tv[2] = (short)bfbits(lo.z); tv[3] = (short)bfbits(lo.w);
            tv[4] = (short)bfbits(hi.x); tv[5] = (short)bfbits(hi.y);
            tv[6] = (short)bfbits(hi.z); tv[7] = (short)bfbits(hi.w);
            a[kk] = tv;
        }
    }

    // ---- phase 4: DFT MFMAs ----
    const unsigned short* bbase = basisT + (trig * 144 + (lane & 15)) * DDIM
                                + ((lane >> 4) << 3);
    const int lrow = (lane >> 4) << 2;
#pragma unroll 1
    for (int n = 0; n < 9; ++n) {
        f32x4 acc = (f32x4){0.f, 0.f, 0.f, 0.f};
#pragma unroll
        for (int kk = 0; kk < 8; ++kk) {
            bf16x8 b = *(const bf16x8*)(bbase + n * 16 * DDIM + kk * 32);
            acc = __builtin_amdgcn_mfma_f32_16x16x32_bf16(a[kk], b, acc, 0, 0, 0);
        }
        const int bin = n * 16 + (lane & 15);
        if (bin <= 128) {   // GUARD: n=8 covers bins 128..143; only 128 is real.
#pragma unroll
            for (int rr = 0; rr < 4; ++rr)
                xch[srcw][trig][lrow + rr][bin] = acc[rr];
        }
    }
    __syncthreads();

    // block reduce of (|fft_c| - |fft_t|)^2 over 16 rows x 129 bins
    {
        const int rr = t >> 4;
        float s = 0.0f;
        for (int b = (t & 15); b < NBINS; b += 16) {
            const float crc = xch[0][0][rr][b], cic = xch[0][1][rr][b];
            const float crt = xch[1][0][rr][b], cit = xch[1][1][rr][b];
            const float d = sqrtf(crc * crc + cic * cic)
                          - sqrtf(crt * crt + cit * cit);
            s += d * d;
        }
        s = wave_red(s);
        if (lane == 0) rbuf[w] = s;
    }
    __syncthreads();
    if (t == 0) {
        freq_part[blockIdx.x] = rbuf[0] + rbuf[1] + rbuf[2] + rbuf[3];
        spat_part[blockIdx.x] = sp4[0] + sp4[1] + sp4[2] + sp4[3];
    }
}

// ---------------------------------------------------------------------------
// Kernel 3: 128x128 bf16 MFMA GEMM, SINGLE-buffer (35 KB LDS -> 4 blocks/CU),
// m97 2-barrier loop, swizzled staging, XCD-aware block swizzle,
// fused exp/mask epilogue -> per-block partial stores.
// ---------------------------------------------------------------------------
#define BM 128
#define BN 128
#define BK 64

__global__ __launch_bounds__(256) void k_gemm(const unsigned short* __restrict__ cnb,
                                              const unsigned short* __restrict__ tnb,
                                              const int* __restrict__ sid,
                                              float* __restrict__ pall,
                                              float* __restrict__ ppos) {
    __shared__ unsigned short As[BM][BK];
    __shared__ unsigned short Bs[BN][BK];
    __shared__ float ps[2][BM][2];          // [colhalf][row][all|pos]
    __shared__ int sidI[BM], sidJ[BN];

    // XCD-aware swizzle: 4096 blocks, 8 XCDs, 512/XCD (bijective: 4096%8==0)
    const int bid = blockIdx.x;
    const int swz = (bid & 7) * 512 + (bid >> 3);
    const int ib  = swz >> 6;
    const int jb  = swz & 63;
    const int i0  = ib * BM;
    const int j0  = jb * BN;

    const int t = threadIdx.x;
    if (t < 128) sidI[t] = sid[i0 + t];
    else         sidJ[t - 128] = sid[j0 + t - 128];

    const int wid  = t >> 6;
    const int lane = t & 63;
    const int wrow = (wid >> 1) * 64;
    const int wcol = (wid & 1) * 64;
    const int rx   = lane & 7;

    f32x4 acc[4][4];
#pragma unroll
    for (int m = 0; m < 4; ++m)
#pragma unroll
        for (int n = 0; n < 4; ++n)
            acc[m][n] = (f32x4){0.f, 0.f, 0.f, 0.f};

    for (int kt = 0; kt < DDIM / BK; ++kt) {
        // stage: linear LDS dest, inverse-swizzled global source
#pragma unroll
        for (int it = 0; it < 4; ++it) {
            const int g  = it * 256 + t;          // 16B granule 0..1023
            const int r  = g >> 3;
            const int sl = g & 7;
            const int sc = ((sl ^ (r & 7)) << 3);
            gload_lds16(cnb + (i0 + r) * DDIM + kt * BK + sc,
                        (char*)&As[0][0] + g * 16);
            gload_lds16(tnb + (j0 + r) * DDIM + kt * BK + sc,
                        (char*)&Bs[0][0] + g * 16);
        }
        __syncthreads();   // drains vmcnt before reads
#pragma unroll
        for (int kk = 0; kk < BK / 32; ++kk) {
            const int kslot = kk * 4 + (lane >> 4);
            bf16x8 af[4], bfr[4];
#pragma unroll
            for (int m = 0; m < 4; ++m) {
                const int row = wrow + m * 16 + (lane & 15);
                af[m] = *(const bf16x8*)((const char*)&As[0][0]
                          + row * 128 + ((kslot ^ rx) << 4));
            }
#pragma unroll
            for (int n = 0; n < 4; ++n) {
                const int row = wcol + n * 16 + (lane & 15);
                bfr[n] = *(const bf16x8*)((const char*)&Bs[0][0]
                          + row * 128 + ((kslot ^ rx) << 4));
            }
#pragma unroll
            for (int m = 0; m < 4; ++m)
#pragma unroll
                for (int n = 0; n < 4; ++n)
                    acc[m][n] = __builtin_amdgcn_mfma_f32_16x16x32_bf16(
                        af[m], bfr[n], acc[m][n], 0, 0, 0);
        }
        __syncthreads();   // all reads done before next stage overwrites
    }

    // epilogue: exp, mask, 16-lane row-reduce, LDS combine, per-block store
    const float invT = 1.0f / 0.07f;
#pragma unroll
    for (int m = 0; m < 4; ++m) {
        const int rbase = wrow + m * 16 + ((lane >> 4) << 2);
        int si[4];
#pragma unroll
        for (int r = 0; r < 4; ++r) si[r] = sidI[rbase + r];
        float rs_all[4] = {0.f, 0.f, 0.f, 0.f};
        float rs_pos[4] = {0.f, 0.f, 0.f, 0.f};
#pragma unroll
        for (int n = 0; n < 4; ++n) {
            const int col = wcol + n * 16 + (lane & 15);
            const int sj = sidJ[col];
#pragma unroll
            for (int r = 0; r < 4; ++r) {
                float e = __expf(acc[m][n][r] * invT);
                rs_all[r] += e;
                rs_pos[r] += (si[r] == sj) ? e : 0.0f;
            }
        }
#pragma unroll
        for (int msk = 1; msk < 16; msk <<= 1) {
#pragma unroll
            for (int r = 0; r < 4; ++r) {
                rs_all[r] += __shfl_xor(rs_all[r], msk, 64);
                rs_pos[r] += __shfl_xor(rs_pos[r], msk, 64);
            }
        }
        if ((lane & 15) == 0) {
#pragma unroll
            for (int r = 0; r < 4; ++r) {
                ps[wid & 1][rbase + r][0] = rs_all[r];
                ps[wid & 1][rbase + r][1] = rs_pos[r];
            }
        }
    }
    __syncthreads();
    if (t < BM) {
        const float sa = ps[0][t][0] + ps[1][t][0];
        const float sp = ps[0][t][1] + ps[1][t][1];
        pall[jb * NROWS + i0 + t] = sa;
        ppos[jb * NROWS + i0 + t] = sp;
    }
}

// ---------------------------------------------------------------------------
// Kernel 4: per-row sum over 64 j-block partials + log terms.
// ---------------------------------------------------------------------------
__global__ __launch_bounds__(256) void k_red(const float* __restrict__ pall,
                                             const float* __restrict__ ppos,
                                             float* __restrict__ contrib) {
    __shared__ float red[256];
    const int row = blockIdx.x * 256 + threadIdx.x;
    float sa = 0.0f, sp = 0.0f;
    for (int jb = 0; jb < 64; ++jb) {
        sa += pall[jb * NROWS + row];
        sp += ppos[jb * NROWS + row];
    }
    red[threadIdx.x] = logf(sa + 1e-8f) - logf(sp);
    __syncthreads();
#pragma unroll
    for (int s = 128; s > 0; s >>= 1) {
        if (threadIdx.x < s) red[threadIdx.x] += red[threadIdx.x + s];
        __syncthreads();
    }
    if (threadIdx.x == 0) contrib[blockIdx.x] = red[0];
}

// ---------------------------------------------------------------------------
// Kernel 5: fold all partials -> 4 outputs
// ---------------------------------------------------------------------------
__global__ __launch_bounds__(256) void k_final(const float* __restrict__ spat_part,
                                               const float* __restrict__ freq_part,
                                               const float* __restrict__ contrib,
                                               float* __restrict__ out) {
    __shared__ float reda[256], redb[256], redc[256];
    float a = 0.0f, b = 0.0f, c = 0.0f;
    for (int i = threadIdx.x; i < 512; i += 256) {
        a += spat_part[i];
        b += freq_part[i];
    }
    if (threadIdx.x < 32) c = contrib[threadIdx.x];
    reda[threadIdx.x] = a; redb[threadIdx.x] = b; redc[threadIdx.x] = c;
    __syncthreads();
#pragma unroll
    for (int s = 128; s > 0; s >>= 1) {
        if (threadIdx.x < s) {
            reda[threadIdx.x] += reda[threadIdx.x + s];
            redb[threadIdx.x] += redb[threadIdx.x + s];
            redc[threadIdx.x] += redc[threadIdx.x + s];
        }
        __syncthreads();
    }
    if (threadIdx.x == 0) {
        float spatial = reda[0] / (float)(NROWS * DDIM);
        float frequency = redb[0] / (float)(NROWS * NBINS);
        float contrastive = redc[0] / (float)NROWS;
        out[0] = spatial + frequency + 0.5f * contrastive;
        out[1] = spatial;
        out[2] = frequency;
        out[3] = contrastive;
    }
}

// ---------------------------------------------------------------------------
extern "C" void kernel_launch(void* const* d_in, const int* in_sizes, int n_in,
                              void* d_out, int out_size, void* d_ws, size_t ws_size,
                              hipStream_t stream) {
    const float* clean = (const float*)d_in[0];
    const float* turb  = (const float*)d_in[1];
    const int*   sids  = (const int*)d_in[2];

    char* ws = (char*)d_ws;
    unsigned short* cnb    = (unsigned short*)ws;                      // 4 MB
    unsigned short* tnb    = (unsigned short*)(ws + 4194304);          // 4 MB
    unsigned short* basisT = (unsigned short*)(ws + 8388608);          // 147 KB
    float* pall      = (float*)(ws + 8650752);                         // 2 MB
    float* ppos      = (float*)(ws + 10747904);                        // 2 MB
    float* spat_part = (float*)(ws + 12845056);                        // 2 KB
    float* freq_part = (float*)(ws + 12849152);                        // 2 KB
    float* contrib   = (float*)(ws + 12853248);                        // 128 B

    hipLaunchKernelGGL(k_basis, dim3(288), dim3(256), 0, stream, basisT);
    hipLaunchKernelGGL(k_prep, dim3(NROWS / 16), dim3(256), 0, stream,
                       clean, turb, basisT, cnb, tnb, spat_part, freq_part);
    hipLaunchKernelGGL(k_gemm, dim3(4096), dim3(256), 0, stream,
                       cnb, tnb, sids, pall, ppos);
    hipLaunchKernelGGL(k_red, dim3(NROWS / 256), dim3(256), 0, stream,
                       pall, ppos, contrib);
    hipLaunchKernelGGL(k_final, dim3(1), dim3(256), 0, stream,
                       spat_part, freq_part, contrib, (float*)d_out);
}